// Round 4
// baseline (95.821 us; speedup 1.0000x reference)
//
#include <hip/hip_runtime.h>
#include <hip/hip_bf16.h>

// DeconvCapsuleLayer fused kernel, round 4.
// conv2d_transpose (votes) via bf16 MFMA + 3-iter dynamic routing, all in
// registers, ZERO LDS bridges (round-3's ds_write->drain->ds_read transposes
// were ~120+cyc serial latency each).
// Round-4 changes:
//   - back to single-layout (no accT): 16 MFMAs/pair, routing reductions via
//     VALU-pipe cross-lane only:
//       * oa-sums: v_add_f32_dpp, 4 chains interleaved in one asm block
//         (dependent DPPs 4 apart -> hazard wait-states satisfied, no s_nops)
//       * ich-join (xor16): v_permlane16_swap_b32 + add (gfx950 VALU crossbar)
//   - MFMA C=0 inline constant (no accvgpr zero-init)
//   - no-max softmax (|logit| <= ~4, f32 exp safe)
//   - XCD-aware bid mapping: b = h&7 -> each XCD owns one batch (3.2MB input
//     fits per-XCD L2); sibling classes adjacent for input reuse
//
// Conv-transpose (stride 2, K=4, SAME -> pad 1): with o = 2*y+py:
//   ky = 2*ty + (py^1), iy = y + py - ty, valid iff 0<=iy<56 (same for x).

typedef __attribute__((ext_vector_type(8))) short bf16x8;
typedef __attribute__((ext_vector_type(4))) float f32x4;

static __device__ __forceinline__ unsigned short f2bfu(float f) {
    union { __hip_bfloat16 h; unsigned short u; } cv;
    cv.h = __float2bfloat16(f);  // RNE
    return cv.u;
}
static __device__ __forceinline__ short f2bf(float f) { return (short)f2bfu(f); }

// Four interleaved 16-lane all-reduce sums (broadcast to all 16 row lanes).
// Stage order per chain: xor1 (quad_perm), xor2 (quad_perm), xor4-equivalent
// (row_half_mirror: valid because quads are uniform after stage 2),
// xor8-equivalent (row_mirror: half-rows uniform after stage 3).
// Chains interleaved 4-wide so dependent DPP ops are >=3 insts apart
// (covers the VALU->DPP 2-wait-state hazard); leading s_nop covers entry.
static __device__ __forceinline__ void dpp_sum16_x4(float& a, float& b,
                                                    float& c, float& d) {
    asm("s_nop 1\n\t"
        "v_add_f32_dpp %0, %0, %0 quad_perm:[1,0,3,2] row_mask:0xf bank_mask:0xf\n\t"
        "v_add_f32_dpp %1, %1, %1 quad_perm:[1,0,3,2] row_mask:0xf bank_mask:0xf\n\t"
        "v_add_f32_dpp %2, %2, %2 quad_perm:[1,0,3,2] row_mask:0xf bank_mask:0xf\n\t"
        "v_add_f32_dpp %3, %3, %3 quad_perm:[1,0,3,2] row_mask:0xf bank_mask:0xf\n\t"
        "v_add_f32_dpp %0, %0, %0 quad_perm:[2,3,0,1] row_mask:0xf bank_mask:0xf\n\t"
        "v_add_f32_dpp %1, %1, %1 quad_perm:[2,3,0,1] row_mask:0xf bank_mask:0xf\n\t"
        "v_add_f32_dpp %2, %2, %2 quad_perm:[2,3,0,1] row_mask:0xf bank_mask:0xf\n\t"
        "v_add_f32_dpp %3, %3, %3 quad_perm:[2,3,0,1] row_mask:0xf bank_mask:0xf\n\t"
        "v_add_f32_dpp %0, %0, %0 row_half_mirror row_mask:0xf bank_mask:0xf\n\t"
        "v_add_f32_dpp %1, %1, %1 row_half_mirror row_mask:0xf bank_mask:0xf\n\t"
        "v_add_f32_dpp %2, %2, %2 row_half_mirror row_mask:0xf bank_mask:0xf\n\t"
        "v_add_f32_dpp %3, %3, %3 row_half_mirror row_mask:0xf bank_mask:0xf\n\t"
        "v_add_f32_dpp %0, %0, %0 row_mirror row_mask:0xf bank_mask:0xf\n\t"
        "v_add_f32_dpp %1, %1, %1 row_mirror row_mask:0xf bank_mask:0xf\n\t"
        "v_add_f32_dpp %2, %2, %2 row_mirror row_mask:0xf bank_mask:0xf\n\t"
        "v_add_f32_dpp %3, %3, %3 row_mirror row_mask:0xf bank_mask:0xf"
        : "+v"(a), "+v"(b), "+v"(c), "+v"(d));
}

// xor16-join for 4 values: p_i += (p_i from the other 16-lane row of the
// 32-half). v_permlane16_swap_b32 exchanges 16-lane rows between the two
// registers; with both registers equal beforehand, p+q yields the row-pair
// sum in every lane regardless of swap direction convention.
static __device__ __forceinline__ void join16_x4(float& p0, float& p1,
                                                 float& p2, float& p3) {
    float q0 = p0, q1 = p1, q2 = p2, q3 = p3;
    asm("s_nop 1\n\t"
        "v_permlane16_swap_b32 %0, %4\n\t"
        "v_permlane16_swap_b32 %1, %5\n\t"
        "v_permlane16_swap_b32 %2, %6\n\t"
        "v_permlane16_swap_b32 %3, %7"
        : "+v"(p0), "+v"(p1), "+v"(p2), "+v"(p3),
          "+v"(q0), "+v"(q1), "+v"(q2), "+v"(q3));
    p0 += q0; p1 += q1; p2 += q2; p3 += q3;
}

__global__ __launch_bounds__(256, 4)
void caps_deconv_route(const float* __restrict__ in, const float* __restrict__ Wt,
                       const float* __restrict__ bia, float* __restrict__ out) {
    const int tid  = threadIdx.x;
    const int lane = tid & 63;
    const int wid  = tid >> 6;

    // XCD-aware mapping: hardware bid h -> (b = h&7, tile = h>>5, cls).
    // XCD = h%8 (round-robin) -> each XCD processes exactly one batch; its
    // 3.2MB input slice fits the 4MB per-XCD L2. Sibling blocks (same tile,
    // different class) are adjacent -> shared input window stays hot.
    const int h    = blockIdx.x;
    const int b    = h & 7;
    const int k    = h >> 3;        // 0..195
    const int tile = k >> 2;        // 0..48
    const int cls  = k & 3;
    const int py = cls >> 1, px = cls & 1;

    // ---- stage weights (this parity class) into LDS as bf16 B-fragments ----
    // LDS image: uint4[(s*4 + ko)*64 + ch], ch = oc*16+oa; each uint4 = 8 bf16
    __shared__ uint4 wlds[1024];  // 16 KB
    for (int t = tid; t < 1024; t += 256) {
        const int s  = t >> 8;
        const int ko = (t >> 6) & 3;
        const int ch = t & 63;
        const int ky = 2*(s >> 1) + (py ^ 1);
        const int kx = 2*(s & 1)  + (px ^ 1);
        const float* wp = Wt + (((ky*4 + kx)*64 + ch)*32 + ko*8);
        const float4 w0 = *(const float4*)(wp);
        const float4 w1 = *(const float4*)(wp + 4);
        uint4 u;
        u.x = ((unsigned)f2bfu(w0.y) << 16) | f2bfu(w0.x);
        u.y = ((unsigned)f2bfu(w0.w) << 16) | f2bfu(w0.z);
        u.z = ((unsigned)f2bfu(w1.y) << 16) | f2bfu(w1.x);
        u.w = ((unsigned)f2bfu(w1.w) << 16) | f2bfu(w1.z);
        wlds[t] = u;
    }
    __syncthreads();

    const int col  = lane & 15;   // oa / N-col
    const int koct = lane >> 4;
    const int wbase = koct*64 + col;

    const int oa    = col;
    const int posl  = lane >> 5;        // C rows: position of the pair
    const int ich   = (lane >> 4) & 1;  // C rows: ic half
    const int a_pos = (lane >> 3) & 1;  // A rows: position
    const int a_ic  = lane & 7;         // A rows: ic

    float bias_v[4];
    #pragma unroll
    for (int oc = 0; oc < 4; ++oc) bias_v[oc] = bia[oc*16 + oa];

    const float* in_base = in + ((size_t)b*56*56*8 + a_ic)*32 + koct*8;

    int p0 = (tile*32 + wid*8) * 2;
    int y  = p0 / 56;
    int x0 = p0 - y*56;   // pairs advance by 2; 56 even -> never crosses rows

    for (int i = 0; i < 8; ++i) {
        const int yy = y + py;
        const int xx = x0 + a_pos + px;

        // ---- A fragments: A[r=pos*8+ic][k=s*32+ci] ----
        bf16x8 af[4];
        #pragma unroll
        for (int s = 0; s < 4; ++s) {
            const int ty = s >> 1, tx = s & 1;
            const int iy = yy - ty;
            const int ix = xx - tx;
            float4 a0 = make_float4(0.f, 0.f, 0.f, 0.f);
            float4 a1 = make_float4(0.f, 0.f, 0.f, 0.f);
            if ((unsigned)iy < 56u && (unsigned)ix < 56u) {
                const float* ap = in_base + (size_t)(iy*56 + ix) * 256;
                a0 = *(const float4*)(ap);
                a1 = *(const float4*)(ap + 4);
            }
            bf16x8 v;
            v[0]=f2bf(a0.x); v[1]=f2bf(a0.y); v[2]=f2bf(a0.z); v[3]=f2bf(a0.w);
            v[4]=f2bf(a1.x); v[5]=f2bf(a1.y); v[6]=f2bf(a1.z); v[7]=f2bf(a1.w);
            af[s] = v;
        }

        // ---- votes: C[16][64] = A*B; first MFMA uses inline C=0 ----
        f32x4 acc[4];
        #pragma unroll
        for (int nt = 0; nt < 4; ++nt) {
            bf16x8 wf = __builtin_bit_cast(bf16x8, wlds[wbase + nt*16]);
            acc[nt] = __builtin_amdgcn_mfma_f32_16x16x32_bf16(
                af[0], wf, (f32x4){0.f, 0.f, 0.f, 0.f}, 0, 0, 0);
        }
        #pragma unroll
        for (int s = 1; s < 4; ++s) {
            #pragma unroll
            for (int nt = 0; nt < 4; ++nt) {
                bf16x8 wf = __builtin_bit_cast(bf16x8, wlds[wbase + s*256 + nt*16]);
                acc[nt] = __builtin_amdgcn_mfma_f32_16x16x32_bf16(af[s], wf, acc[nt], 0, 0, 0);
            }
        }
        // lane (pos=posl, ich, oa): acc[oc][q] = votes[ic=ich*4+q][oc][oa]

        // ---- routing iteration 1 (logits=0 -> route=0.25 exactly) ----
        float act[4], p[4], sq[4];
        #pragma unroll
        for (int oc = 0; oc < 4; ++oc)
            p[oc] = acc[oc][0] + acc[oc][1] + acc[oc][2] + acc[oc][3];
        join16_x4(p[0], p[1], p[2], p[3]);
        #pragma unroll
        for (int oc = 0; oc < 4; ++oc) {
            p[oc] = fmaf(0.25f, p[oc], bias_v[oc]);
            sq[oc] = p[oc] * p[oc];
        }
        dpp_sum16_x4(sq[0], sq[1], sq[2], sq[3]);
        #pragma unroll
        for (int oc = 0; oc < 4; ++oc)
            act[oc] = p[oc] * (sqrtf(sq[oc]) * __builtin_amdgcn_rcpf(1.f + sq[oc]));

        // logits after iter 1: logit[q][oc] = sum_oa votes*act
        float logit[4][4];
        #pragma unroll
        for (int q = 0; q < 4; ++q)
            #pragma unroll
            for (int oc = 0; oc < 4; ++oc)
                logit[q][oc] = acc[oc][q] * act[oc];
        #pragma unroll
        for (int q = 0; q < 4; ++q)
            dpp_sum16_x4(logit[q][0], logit[q][1], logit[q][2], logit[q][3]);

        // ---- iterations 2 and 3 ----
        #pragma unroll
        for (int it = 1; it < 3; ++it) {
            // no-max softmax over oc per ic row (|logit| small by construction)
            float route[4][4];
            #pragma unroll
            for (int q = 0; q < 4; ++q) {
                float e0 = __expf(logit[q][0]), e1 = __expf(logit[q][1]);
                float e2 = __expf(logit[q][2]), e3 = __expf(logit[q][3]);
                float inv = __builtin_amdgcn_rcpf(e0 + e1 + e2 + e3);
                route[q][0] = e0*inv; route[q][1] = e1*inv;
                route[q][2] = e2*inv; route[q][3] = e3*inv;
            }
            #pragma unroll
            for (int oc = 0; oc < 4; ++oc) {
                float t = route[0][oc] * acc[oc][0];
                t = fmaf(route[1][oc], acc[oc][1], t);
                t = fmaf(route[2][oc], acc[oc][2], t);
                t = fmaf(route[3][oc], acc[oc][3], t);
                p[oc] = t;
            }
            join16_x4(p[0], p[1], p[2], p[3]);
            #pragma unroll
            for (int oc = 0; oc < 4; ++oc) {
                p[oc] += bias_v[oc];
                sq[oc] = p[oc] * p[oc];
            }
            dpp_sum16_x4(sq[0], sq[1], sq[2], sq[3]);
            #pragma unroll
            for (int oc = 0; oc < 4; ++oc)
                act[oc] = p[oc] * (sqrtf(sq[oc]) * __builtin_amdgcn_rcpf(1.f + sq[oc]));
            if (it == 1) {
                float upd[4][4];
                #pragma unroll
                for (int q = 0; q < 4; ++q)
                    #pragma unroll
                    for (int oc = 0; oc < 4; ++oc)
                        upd[q][oc] = acc[oc][q] * act[oc];
                #pragma unroll
                for (int q = 0; q < 4; ++q) {
                    dpp_sum16_x4(upd[q][0], upd[q][1], upd[q][2], upd[q][3]);
                    #pragma unroll
                    for (int oc = 0; oc < 4; ++oc) logit[q][oc] += upd[q][oc];
                }
            }
        }

        // ---- store activation (ich==0 lanes carry each position once) ----
        if (ich == 0) {
            const int oy = 2*y + py;
            const int ox = 2*(x0 + posl) + px;
            float* op = out + ((((size_t)b*112 + oy)*112 + ox)*64 + oa);
            #pragma unroll
            for (int oc = 0; oc < 4; ++oc) op[oc*16] = act[oc];
        }

        x0 += 2;
        if (x0 >= 56) { x0 -= 56; ++y; }
    }
}

extern "C" void kernel_launch(void* const* d_in, const int* in_sizes, int n_in,
                              void* d_out, int out_size, void* d_ws, size_t ws_size,
                              hipStream_t stream) {
    const float* in  = (const float*)d_in[0];
    const float* Wt  = (const float*)d_in[1];
    const float* bia = (const float*)d_in[2];
    float* out = (float*)d_out;
    hipLaunchKernelGGL(caps_deconv_route, dim3(1568), dim3(256), 0, stream,
                       in, Wt, bia, out);
}

// Round 5
// 79.348 us; speedup vs baseline: 1.2076x; 1.2076x over previous
//
#include <hip/hip_runtime.h>
#include <hip/hip_bf16.h>

// DeconvCapsuleLayer fused kernel, round 5.
// R3 dual-layout structure (acc for preact/squash, accT for softmax/logits,
// small per-wave LDS bridges) + R4's XCD-aware block mapping (FETCH 95->13MB)
// + grid x2 (4 pairs/wave -> 12544 waves, better occupancy + smaller tail)
// + DS shuffles replaced with VALU permlane16/32 swaps + no-max softmax.
//
// Conv-transpose (stride 2, K=4, SAME -> pad 1): with o = 2*y+py:
//   ky = 2*ty + (py^1), iy = y + py - ty, valid iff 0<=iy<56 (same for x).

typedef __attribute__((ext_vector_type(8))) short bf16x8;
typedef __attribute__((ext_vector_type(4))) float f32x4;

static __device__ __forceinline__ unsigned short f2bfu(float f) {
    union { __hip_bfloat16 h; unsigned short u; } cv;
    cv.h = __float2bfloat16(f);  // RNE
    return cv.u;
}
static __device__ __forceinline__ short f2bf(float f) { return (short)f2bfu(f); }

// Four interleaved 16-lane all-reduce sums (broadcast to all 16 row lanes).
// Single-inst DPP-add stages, chains 4 apart (hazard wait states covered).
static __device__ __forceinline__ void dpp_sum16_x4(float& a, float& b,
                                                    float& c, float& d) {
    asm("s_nop 1\n\t"
        "v_add_f32_dpp %0, %0, %0 quad_perm:[1,0,3,2] row_mask:0xf bank_mask:0xf\n\t"
        "v_add_f32_dpp %1, %1, %1 quad_perm:[1,0,3,2] row_mask:0xf bank_mask:0xf\n\t"
        "v_add_f32_dpp %2, %2, %2 quad_perm:[1,0,3,2] row_mask:0xf bank_mask:0xf\n\t"
        "v_add_f32_dpp %3, %3, %3 quad_perm:[1,0,3,2] row_mask:0xf bank_mask:0xf\n\t"
        "v_add_f32_dpp %0, %0, %0 quad_perm:[2,3,0,1] row_mask:0xf bank_mask:0xf\n\t"
        "v_add_f32_dpp %1, %1, %1 quad_perm:[2,3,0,1] row_mask:0xf bank_mask:0xf\n\t"
        "v_add_f32_dpp %2, %2, %2 quad_perm:[2,3,0,1] row_mask:0xf bank_mask:0xf\n\t"
        "v_add_f32_dpp %3, %3, %3 quad_perm:[2,3,0,1] row_mask:0xf bank_mask:0xf\n\t"
        "v_add_f32_dpp %0, %0, %0 row_half_mirror row_mask:0xf bank_mask:0xf\n\t"
        "v_add_f32_dpp %1, %1, %1 row_half_mirror row_mask:0xf bank_mask:0xf\n\t"
        "v_add_f32_dpp %2, %2, %2 row_half_mirror row_mask:0xf bank_mask:0xf\n\t"
        "v_add_f32_dpp %3, %3, %3 row_half_mirror row_mask:0xf bank_mask:0xf\n\t"
        "v_add_f32_dpp %0, %0, %0 row_mirror row_mask:0xf bank_mask:0xf\n\t"
        "v_add_f32_dpp %1, %1, %1 row_mirror row_mask:0xf bank_mask:0xf\n\t"
        "v_add_f32_dpp %2, %2, %2 row_mirror row_mask:0xf bank_mask:0xf\n\t"
        "v_add_f32_dpp %3, %3, %3 row_mirror row_mask:0xf bank_mask:0xf"
        : "+v"(a), "+v"(b), "+v"(c), "+v"(d));
}

// xor16 pair-sum for 4 values (v_permlane16_swap + add; exchange direction
// irrelevant since both registers start equal).
static __device__ __forceinline__ void join16_x4(float& p0, float& p1,
                                                 float& p2, float& p3) {
    float q0 = p0, q1 = p1, q2 = p2, q3 = p3;
    asm("s_nop 1\n\t"
        "v_permlane16_swap_b32 %0, %4\n\t"
        "v_permlane16_swap_b32 %1, %5\n\t"
        "v_permlane16_swap_b32 %2, %6\n\t"
        "v_permlane16_swap_b32 %3, %7"
        : "+v"(p0), "+v"(p1), "+v"(p2), "+v"(p3),
          "+v"(q0), "+v"(q1), "+v"(q2), "+v"(q3));
    p0 += q0; p1 += q1; p2 += q2; p3 += q3;
}

// xor32 pair-sum for 4 values.
static __device__ __forceinline__ void join32_x4(float& p0, float& p1,
                                                 float& p2, float& p3) {
    float q0 = p0, q1 = p1, q2 = p2, q3 = p3;
    asm("s_nop 1\n\t"
        "v_permlane32_swap_b32 %0, %4\n\t"
        "v_permlane32_swap_b32 %1, %5\n\t"
        "v_permlane32_swap_b32 %2, %6\n\t"
        "v_permlane32_swap_b32 %3, %7"
        : "+v"(p0), "+v"(p1), "+v"(p2), "+v"(p3),
          "+v"(q0), "+v"(q1), "+v"(q2), "+v"(q3));
    p0 += q0; p1 += q1; p2 += q2; p3 += q3;
}

__global__ __launch_bounds__(256, 4)
void caps_deconv_route(const float* __restrict__ in, const float* __restrict__ Wt,
                       const float* __restrict__ bia, float* __restrict__ out) {
    const int tid  = threadIdx.x;
    const int lane = tid & 63;
    const int wid  = tid >> 6;

    // XCD-aware mapping: b = h&7 -> each XCD owns one batch (3.2MB input fits
    // its 4MB L2); sibling classes of a segment adjacent on the same XCD.
    const int h    = blockIdx.x;       // grid = 3136
    const int b    = h & 7;
    const int k    = h >> 3;           // 0..391
    const int seg  = k >> 2;           // 0..97 (16 pairs each)
    const int cls  = k & 3;
    const int py = cls >> 1, px = cls & 1;

    // ---- stage weights (this parity class) into LDS as bf16 B-fragments ----
    // uint4[(s*4 + ko)*64 + ch], ch = oc*16+oa; each uint4 = 8 bf16 (ci octet)
    __shared__ uint4 wlds[1024];        // 16 KB
    __shared__ float sw[4][192];        // per-wave bridge scratch (3 KB)
    for (int t = tid; t < 1024; t += 256) {
        const int s  = t >> 8;
        const int ko = (t >> 6) & 3;
        const int ch = t & 63;
        const int ky = 2*(s >> 1) + (py ^ 1);
        const int kx = 2*(s & 1)  + (px ^ 1);
        const float* wp = Wt + (((ky*4 + kx)*64 + ch)*32 + ko*8);
        const float4 w0 = *(const float4*)(wp);
        const float4 w1 = *(const float4*)(wp + 4);
        uint4 u;
        u.x = ((unsigned)f2bfu(w0.y) << 16) | f2bfu(w0.x);
        u.y = ((unsigned)f2bfu(w0.w) << 16) | f2bfu(w0.z);
        u.z = ((unsigned)f2bfu(w1.y) << 16) | f2bfu(w1.x);
        u.w = ((unsigned)f2bfu(w1.w) << 16) | f2bfu(w1.z);
        wlds[t] = u;
    }
    __syncthreads();

    const int col  = lane & 15;   // orig: oa | T: pi
    const int koct = lane >> 4;
    const int wbase = koct*64 + col;

    const int oa    = col;
    const int posl  = lane >> 5;        // orig C rows: position of the pair
    const int ich   = (lane >> 4) & 1;  // orig C rows: ic half
    const int a_pos = (lane >> 3) & 1;  // A rows: position
    const int a_ic  = lane & 7;         // A rows: ic
    const int pi    = col;              // T cols: pos*8+ic
    const int g     = koct;             // T rows: oa group (oa = g*4+r)
    const int posT  = pi >> 3;

    float bias_v[4];
    #pragma unroll
    for (int oc = 0; oc < 4; ++oc) bias_v[oc] = bia[oc*16 + oa];

    float* swa = sw[wid];        // act bridge: [pos][oc][oa] = 128 f32
    float* swr = sw[wid] + 128;  // route bridge: [pi][oc] = 64 f32

    const float* in_base = in + ((size_t)b*56*56*8 + a_ic)*32 + koct*8;

    int p0v = (seg*16 + wid*4) * 2;
    int y  = p0v / 56;
    int x0 = p0v - y*56;   // pairs advance by 2; 56 even -> never crosses rows

    for (int i = 0; i < 4; ++i) {
        const int yy = y + py;
        const int xx = x0 + a_pos + px;

        // ---- A fragments: A[r=pos*8+ic][k=s*32+ci] ----
        bf16x8 af[4];
        #pragma unroll
        for (int s = 0; s < 4; ++s) {
            const int ty = s >> 1, tx = s & 1;
            const int iy = yy - ty;
            const int ix = xx - tx;
            float4 a0 = make_float4(0.f, 0.f, 0.f, 0.f);
            float4 a1 = make_float4(0.f, 0.f, 0.f, 0.f);
            if ((unsigned)iy < 56u && (unsigned)ix < 56u) {
                const float* ap = in_base + (size_t)(iy*56 + ix) * 256;
                a0 = *(const float4*)(ap);
                a1 = *(const float4*)(ap + 4);
            }
            bf16x8 v;
            v[0]=f2bf(a0.x); v[1]=f2bf(a0.y); v[2]=f2bf(a0.z); v[3]=f2bf(a0.w);
            v[4]=f2bf(a1.x); v[5]=f2bf(a1.y); v[6]=f2bf(a1.z); v[7]=f2bf(a1.w);
            af[s] = v;
        }

        // ---- votes both ways (C=0 inline on first MFMA of each chain) ----
        f32x4 acc[4], accT[4];
        #pragma unroll
        for (int nt = 0; nt < 4; ++nt) {
            bf16x8 wf = __builtin_bit_cast(bf16x8, wlds[wbase + nt*16]);
            acc[nt]  = __builtin_amdgcn_mfma_f32_16x16x32_bf16(
                af[0], wf, (f32x4){0.f,0.f,0.f,0.f}, 0, 0, 0);
            accT[nt] = __builtin_amdgcn_mfma_f32_16x16x32_bf16(
                wf, af[0], (f32x4){0.f,0.f,0.f,0.f}, 0, 0, 0);
        }
        #pragma unroll
        for (int s = 1; s < 4; ++s) {
            #pragma unroll
            for (int nt = 0; nt < 4; ++nt) {
                bf16x8 wf = __builtin_bit_cast(bf16x8, wlds[wbase + s*256 + nt*16]);
                acc[nt]  = __builtin_amdgcn_mfma_f32_16x16x32_bf16(af[s], wf, acc[nt], 0, 0, 0);
                accT[nt] = __builtin_amdgcn_mfma_f32_16x16x32_bf16(wf, af[s], accT[nt], 0, 0, 0);
            }
        }
        // orig: lane(posl,ich,oa): acc[oc][q]  = votes[ic=ich*4+q][oc][oa]
        // T:    lane(pi,g):        accT[oc][r] = votes[pi][oc][oa=g*4+r]

        // ---- iter 1 (logits=0 -> route=0.25 exactly) ----
        float p[4], sq[4], act[4];
        #pragma unroll
        for (int oc = 0; oc < 4; ++oc)
            p[oc] = (acc[oc][0] + acc[oc][1]) + (acc[oc][2] + acc[oc][3]);
        join16_x4(p[0], p[1], p[2], p[3]);          // join ic halves
        #pragma unroll
        for (int oc = 0; oc < 4; ++oc) {
            p[oc] = fmaf(0.25f, p[oc], bias_v[oc]);
            sq[oc] = p[oc] * p[oc];
        }
        dpp_sum16_x4(sq[0], sq[1], sq[2], sq[3]);   // norm^2 over oa
        #pragma unroll
        for (int oc = 0; oc < 4; ++oc)
            act[oc] = p[oc] * (sqrtf(sq[oc]) * __builtin_amdgcn_rcpf(1.f + sq[oc]));

        // act -> T layout
        if (ich == 0) {
            #pragma unroll
            for (int oc = 0; oc < 4; ++oc) swa[posl*64 + oc*16 + oa] = act[oc];
        }
        asm volatile("s_waitcnt lgkmcnt(0)" ::: "memory");
        float logit[4];
        #pragma unroll
        for (int oc = 0; oc < 4; ++oc) {
            float4 at = *(const float4*)&swa[posT*64 + oc*16 + g*4];
            float t = accT[oc][0]*at.x;
            t = fmaf(accT[oc][1], at.y, t);
            t = fmaf(accT[oc][2], at.z, t);
            t = fmaf(accT[oc][3], at.w, t);
            logit[oc] = t;
        }
        join16_x4(logit[0], logit[1], logit[2], logit[3]);  // sum over g pairs
        join32_x4(logit[0], logit[1], logit[2], logit[3]);  // sum across halves

        // ---- iterations 2 and 3 ----
        #pragma unroll
        for (int it = 1; it < 3; ++it) {
            // per-lane softmax over oc (lane owns pi); no-max (|logit| small)
            float e0 = __expf(logit[0]), e1 = __expf(logit[1]);
            float e2 = __expf(logit[2]), e3 = __expf(logit[3]);
            float inv = __builtin_amdgcn_rcpf((e0 + e1) + (e2 + e3));
            if (lane < 16) {
                float4 rt = make_float4(e0*inv, e1*inv, e2*inv, e3*inv);
                *(float4*)&swr[pi*4] = rt;
            }
            asm volatile("s_waitcnt lgkmcnt(0)" ::: "memory");
            const int rb = (posl*8 + ich*4) * 4;
            float4 rq0 = *(const float4*)&swr[rb];
            float4 rq1 = *(const float4*)&swr[rb + 4];
            float4 rq2 = *(const float4*)&swr[rb + 8];
            float4 rq3 = *(const float4*)&swr[rb + 12];

            p[0] = fmaf(rq3.x, acc[0][3], fmaf(rq2.x, acc[0][2],
                   fmaf(rq1.x, acc[0][1], rq0.x*acc[0][0])));
            p[1] = fmaf(rq3.y, acc[1][3], fmaf(rq2.y, acc[1][2],
                   fmaf(rq1.y, acc[1][1], rq0.y*acc[1][0])));
            p[2] = fmaf(rq3.z, acc[2][3], fmaf(rq2.z, acc[2][2],
                   fmaf(rq1.z, acc[2][1], rq0.z*acc[2][0])));
            p[3] = fmaf(rq3.w, acc[3][3], fmaf(rq2.w, acc[3][2],
                   fmaf(rq1.w, acc[3][1], rq0.w*acc[3][0])));
            join16_x4(p[0], p[1], p[2], p[3]);
            #pragma unroll
            for (int oc = 0; oc < 4; ++oc) {
                p[oc] += bias_v[oc];
                sq[oc] = p[oc] * p[oc];
            }
            dpp_sum16_x4(sq[0], sq[1], sq[2], sq[3]);
            #pragma unroll
            for (int oc = 0; oc < 4; ++oc)
                act[oc] = p[oc] * (sqrtf(sq[oc]) * __builtin_amdgcn_rcpf(1.f + sq[oc]));

            if (it == 1) {
                if (ich == 0) {
                    #pragma unroll
                    for (int oc = 0; oc < 4; ++oc) swa[posl*64 + oc*16 + oa] = act[oc];
                }
                asm volatile("s_waitcnt lgkmcnt(0)" ::: "memory");
                float upd[4];
                #pragma unroll
                for (int oc = 0; oc < 4; ++oc) {
                    float4 at = *(const float4*)&swa[posT*64 + oc*16 + g*4];
                    float t = accT[oc][0]*at.x;
                    t = fmaf(accT[oc][1], at.y, t);
                    t = fmaf(accT[oc][2], at.z, t);
                    t = fmaf(accT[oc][3], at.w, t);
                    upd[oc] = t;
                }
                join16_x4(upd[0], upd[1], upd[2], upd[3]);
                join32_x4(upd[0], upd[1], upd[2], upd[3]);
                #pragma unroll
                for (int oc = 0; oc < 4; ++oc) logit[oc] += upd[oc];
            }
        }

        // ---- store activation (ich==0 lanes carry each position once) ----
        if (ich == 0) {
            const int oy = 2*y + py;
            const int ox = 2*(x0 + posl) + px;
            float* op = out + ((((size_t)b*112 + oy)*112 + ox)*64 + oa);
            #pragma unroll
            for (int oc = 0; oc < 4; ++oc) op[oc*16] = act[oc];
        }

        x0 += 2;
        if (x0 >= 56) { x0 -= 56; ++y; }
    }
}

extern "C" void kernel_launch(void* const* d_in, const int* in_sizes, int n_in,
                              void* d_out, int out_size, void* d_ws, size_t ws_size,
                              hipStream_t stream) {
    const float* in  = (const float*)d_in[0];
    const float* Wt  = (const float*)d_in[1];
    const float* bia = (const float*)d_in[2];
    float* out = (float*)d_out;
    hipLaunchKernelGGL(caps_deconv_route, dim3(3136), dim3(256), 0, stream,
                       in, Wt, bia, out);
}